// Round 7
// baseline (282.694 us; speedup 1.0000x reference)
//
#include <hip/hip_runtime.h>

// VQ-VAE VectorQuantizer: z (32,256,32,32) f32, emb (1024,256) f32
// -> d_out: [32768 floats: argmin indices] + [1 float: loss]
//
// R7 (on R6's conflict-free swizzled MFMA kernel):
//  - XCD-aware block map: ct=(blk>>3)&7, rowtile=((blk>>6)<<3)|(blk&7) ->
//    8 consecutive blocks per XCD share one rowtile's A-tile via XCD L2
//    (R6: 133.7 MB FETCH ~ 4x re-fetch across XCDs).
//  - 3-term bf16 split: dot ~= a1b1 + a1b2 + a2b1 (drop a2b2, |err|<=1.1e-6
//    in d, << GAP 1.5e-4; exact-f64 recheck still guards narrow-gap rows).
//  - recheck: 8 rows/block (halves embT traffic per row).
//  - prep_e + prep_z merged into one launch.
// Numerics: d = fl(fl(t1+sume)-fl(2*dot)), numpy-pairwise sums, packed
// (f32bits<<32|j) first-occurrence argmin -- validated absmax 0 R4-R6.

#define NE   1024
#define DIM  256
#define BHW  32768
#define CST  1024
#define BST  262144
#define NTH  256
#define MT   128
#define NT   128
#define KT   16
#define RT   8
#define CTY  8
#define ZSTR 160
#define NKT  (DIM / KT)
#define GAP_MFMA 1.5e-4f
#define GAP_F32  2.5e-4f

// workspace offsets (bytes)
#define OFF_SUME   0
#define OFF_LOSS   4096
#define OFF_CNT    4112
#define OFF_T1     8192
#define OFF_BESTD  139264
#define OFF_LIST   270336
#define OFF_EMBT   401408
#define OFF_PART1  1449984
#define OFF_PART2  3547136
#define OFF_ZA     5242880
#define OFF_EB     38797312
#define WS_FAST_NEED 40894464ull

typedef unsigned long long ull;
typedef __attribute__((ext_vector_type(8))) short bf16x8;
typedef __attribute__((ext_vector_type(4))) float f32x4;

__device__ __forceinline__ unsigned short bf16rne(float x) {
    unsigned u = __float_as_uint(x);
    return (unsigned short)((u + 0x7fffu + ((u >> 16) & 1u)) >> 16);
}

__device__ __forceinline__ void gll16(const void* g, void* l) {
    __builtin_amdgcn_global_load_lds(
        (const __attribute__((address_space(1))) unsigned int*)g,
        (__attribute__((address_space(3))) unsigned int*)l, 16, 0, 0);
}

__device__ __forceinline__ float keyhi(ull k) {
    return __uint_as_float((unsigned)(k >> 32));
}
__device__ __forceinline__ void kmerge(ull& m1, float& m2, ull x1, float x2) {
    if (x1 < m1) { m2 = fminf(x2, keyhi(m1)); m1 = x1; }
    else          m2 = fminf(m2, keyhi(x1));
}

__device__ __forceinline__ float np_pw128_sq_contig(const float* p) {
    float r[8];
#pragma unroll
    for (int k = 0; k < 8; ++k) r[k] = __fmul_rn(p[k], p[k]);
    for (int i = 8; i < 128; i += 8) {
#pragma unroll
        for (int k = 0; k < 8; ++k)
            r[k] = __fadd_rn(r[k], __fmul_rn(p[i + k], p[i + k]));
    }
    return __fadd_rn(__fadd_rn(__fadd_rn(r[0], r[1]), __fadd_rn(r[2], r[3])),
                     __fadd_rn(__fadd_rn(r[4], r[5]), __fadd_rn(r[6], r[7])));
}

// ---- merged prep: blocks 0..127 = e-side, 128.. = z-side -------------------
// Eb layout [kt 16][j 1024][pos 32]: kt<8 = b1(c=kt*32+pos), kt>=8 = b2.
// Za layout [kt 16][n 32768][32]:   kt<8 = a1,                kt>=8 = a2.
__global__ __launch_bounds__(NTH) void vq_prep(const float* __restrict__ emb,
                                               const float* __restrict__ z,
                                               float* __restrict__ sume,
                                               float* __restrict__ embT,
                                               unsigned short* __restrict__ Eb,
                                               unsigned short* __restrict__ Za,
                                               float* __restrict__ t1,
                                               double* __restrict__ loss_acc,
                                               int* __restrict__ cnt,
                                               int doEb) {
    __shared__ float zt[256 * 66];
    const int tid = threadIdx.x;

    if (blockIdx.x < 128) {
        // ---------------- e-side ----------------
        if (blockIdx.x == 0 && tid == 0) { *loss_acc = 0.0; *cnt = 0; }
        const int j0   = blockIdx.x * 8;
        const int jloc = tid >> 5;
        const int c0   = (tid & 31) * 8;
        const int j    = j0 + jloc;

        const float4* gp = (const float4*)(emb + (size_t)j * DIM + c0);
        float4 v0 = gp[0], v1 = gp[1];
        float v[8] = {v0.x, v0.y, v0.z, v0.w, v1.x, v1.y, v1.z, v1.w};

#pragma unroll
        for (int k = 0; k < 8; ++k) zt[jloc * 264 + c0 + k] = v[k];

        if (doEb) {
            bf16x8 p1, p2;
#pragma unroll
            for (int k = 0; k < 8; ++k) {
                unsigned short b1 = bf16rne(v[k]);
                float b1f = __uint_as_float((unsigned)b1 << 16);
                unsigned short b2 = bf16rne(__fsub_rn(v[k], b1f));
                p1[k] = (short)b1;
                p2[k] = (short)b2;
            }
            const int kta = c0 >> 5, pos = c0 & 31;
            *(bf16x8*)(Eb + (size_t)kta * 32768 + (size_t)j * 32 + pos)       = p1;
            *(bf16x8*)(Eb + (size_t)(kta + 8) * 32768 + (size_t)j * 32 + pos) = p2;
        }
        __syncthreads();
        {
            float col[8];
#pragma unroll
            for (int r = 0; r < 8; ++r) col[r] = zt[r * 264 + tid];
            float4 w0 = {col[0], col[1], col[2], col[3]};
            float4 w1 = {col[4], col[5], col[6], col[7]};
            *(float4*)(embT + (size_t)tid * NE + j0)     = w0;
            *(float4*)(embT + (size_t)tid * NE + j0 + 4) = w1;
        }
        if (tid < 8) {
            const float* p = &zt[tid * 264];
            sume[j0 + tid] = __fadd_rn(np_pw128_sq_contig(p),
                                       np_pw128_sq_contig(p + 128));
        }
        return;
    }

    // ---------------- z-side ----------------
    const int zb = blockIdx.x - 128;
    const int b = zb >> 4, hw0 = (zb & 15) * 64;
    const int idx = tid & 63, cq = tid >> 6;
    for (int c = cq * 64; c < cq * 64 + 64; ++c)
        zt[c * 66 + idx] = z[(size_t)b * BST + (size_t)c * CST + hw0 + idx];
    __syncthreads();
    if (tid < 64) {  // numpy-pairwise sum(z^2) per row, exact order
        float r[8], h[2];
#pragma unroll
        for (int half = 0; half < 2; ++half) {
            int c0 = half * 128;
#pragma unroll
            for (int k = 0; k < 8; ++k) {
                float v = zt[(c0 + k) * 66 + tid];
                r[k] = __fmul_rn(v, v);
            }
            for (int c = 8; c < 128; ++c) {
                float v = zt[(c0 + c) * 66 + tid];
                r[c & 7] = __fadd_rn(r[c & 7], __fmul_rn(v, v));
            }
            h[half] = __fadd_rn(
                __fadd_rn(__fadd_rn(r[0], r[1]), __fadd_rn(r[2], r[3])),
                __fadd_rn(__fadd_rn(r[4], r[5]), __fadd_rn(r[6], r[7])));
        }
        t1[b * 1024 + hw0 + tid] = __fadd_rn(h[0], h[1]);
    }
    const int l = tid & 63, seg = tid >> 6;
    const int rloc = seg * 16 + (l >> 2), piece = l & 3;
    const int n = b * 1024 + hw0 + rloc;
    for (int kt = 0; kt < 16; ++kt) {
        bf16x8 pack;
        int cbase = (kt & 7) * 32 + piece * 8;
#pragma unroll
        for (int jj = 0; jj < 8; ++jj) {
            float zf = zt[(cbase + jj) * 66 + rloc];
            unsigned short a1 = bf16rne(zf);
            unsigned short v = a1;
            if (kt >= 8) {
                float a1f = __uint_as_float((unsigned)a1 << 16);
                v = bf16rne(__fsub_rn(zf, a1f));
            }
            pack[jj] = (short)v;
        }
        *(bf16x8*)(Za + (size_t)kt * 1048576 + (size_t)n * 32 + piece * 8) = pack;
    }
}

// ---- MFMA distance GEMM: 128x128 tile, swizzled LDS, 3-term, XCD-mapped ----
__global__ __launch_bounds__(NTH) void vq_mfma(const unsigned short* __restrict__ Za,
                                               const unsigned short* __restrict__ Eb,
                                               const float* __restrict__ sume,
                                               const float* __restrict__ t1g,
                                               ull* __restrict__ part1,
                                               float* __restrict__ part2) {
    __shared__ __align__(16) unsigned short As[8192];  // lo|hi halves, swizzled
    __shared__ __align__(16) unsigned short Bs[8192];
    __shared__ ull   red1[128];
    __shared__ float red2[128];

    const int tid = threadIdx.x;
    const int w = tid >> 6, lane = tid & 63;
    const int wr = w & 1, wc = w >> 1;
    const int c15 = lane & 15, q = lane >> 4;
    // XCD-aware map: XCD = blk%8 (round-robin heuristic). 8 consecutive
    // blocks on one XCD = one rowtile x all 8 cts -> A-tile L2 reuse.
    const int blk = blockIdx.x;
    const int ct = (blk >> 3) & 7;
    const int rowtile = ((blk >> 6) << 3) | (blk & 7);
    const int row0 = rowtile * MT;

    const int perm = (lane >> 2) * 32 + (((lane & 3) ^ ((lane >> 3) & 3)) * 8);
    const int qs = (q ^ ((c15 >> 1) & 3)) * 8;

    f32x4 acc[4][4];
#pragma unroll
    for (int i = 0; i < 4; ++i)
#pragma unroll
        for (int jb = 0; jb < 4; ++jb) acc[i][jb] = (f32x4){0.f, 0.f, 0.f, 0.f};

    const int s0 = w * 2;
    for (int ktp = 0; ktp < 8; ++ktp) {
        __syncthreads();
        {
            const unsigned short* gAlo = Za + (size_t)ktp * 1048576 + (size_t)row0 * 32;
            const unsigned short* gAhi = gAlo + 8u * 1048576u;
            const unsigned short* gBlo = Eb + (size_t)ktp * 32768 + (size_t)ct * 4096;
            const unsigned short* gBhi = gBlo + 8u * 32768u;
#pragma unroll
            for (int ss = 0; ss < 2; ++ss) {
                const int s = s0 + ss;
                gll16(gAlo + s * 512 + perm, (void*)&As[s * 512]);
                gll16(gAhi + s * 512 + perm, (void*)&As[4096 + s * 512]);
                gll16(gBlo + s * 512 + perm, (void*)&Bs[s * 512]);
                gll16(gBhi + s * 512 + perm, (void*)&Bs[4096 + s * 512]);
            }
        }
        __syncthreads();

        bf16x8 bl[4], bh[4];
#pragma unroll
        for (int jb = 0; jb < 4; ++jb) {
            const int nn = (wc * 64 + jb * 16 + c15) * 32 + qs;
            bl[jb] = *(const bf16x8*)&Bs[nn];
            bh[jb] = *(const bf16x8*)&Bs[4096 + nn];
        }
#pragma unroll
        for (int i = 0; i < 4; ++i) {
            const int mm = (wr * 64 + i * 16 + c15) * 32 + qs;
            bf16x8 al = *(const bf16x8*)&As[mm];
            bf16x8 ah = *(const bf16x8*)&As[4096 + mm];
#pragma unroll
            for (int jb = 0; jb < 4; ++jb) {
                acc[i][jb] = __builtin_amdgcn_mfma_f32_16x16x32_bf16(
                    al, bl[jb], acc[i][jb], 0, 0, 0);
                acc[i][jb] = __builtin_amdgcn_mfma_f32_16x16x32_bf16(
                    al, bh[jb], acc[i][jb], 0, 0, 0);
                acc[i][jb] = __builtin_amdgcn_mfma_f32_16x16x32_bf16(
                    ah, bl[jb], acc[i][jb], 0, 0, 0);
            }
        }
    }

    // epilogue: d = fl(fl(t1+sume) - fl(2*dot)); per-row best/2nd over 128 codes
    float sme[4];
#pragma unroll
    for (int jb = 0; jb < 4; ++jb)
        sme[jb] = sume[ct * 128 + wc * 64 + jb * 16 + c15];

    ull   mm1[4][4];
    float mm2[4][4];
#pragma unroll
    for (int i = 0; i < 4; ++i) {
#pragma unroll
        for (int reg = 0; reg < 4; ++reg) {
            int row = row0 + wr * 64 + i * 16 + q * 4 + reg;
            float t1v = t1g[row];
            ull m1 = ~0ull;
            float m2 = 3.4e38f;
#pragma unroll
            for (int jb = 0; jb < 4; ++jb) {
                float d = __fsub_rn(__fadd_rn(t1v, sme[jb]),
                                    __fmul_rn(2.0f, acc[i][jb][reg]));
                ull key = ((ull)__float_as_uint(d) << 32) |
                          (unsigned)(ct * 128 + wc * 64 + jb * 16 + c15);
                kmerge(m1, m2, key, 3.4e38f);
            }
#pragma unroll
            for (int m = 1; m < 16; m <<= 1) {
                ull x1 = __shfl_xor(m1, m);
                float x2 = __shfl_xor(m2, m);
                kmerge(m1, m2, x1, x2);
            }
            mm1[i][reg] = m1;
            mm2[i][reg] = m2;
        }
    }
    if (wc == 0 && c15 == 0) {
#pragma unroll
        for (int i = 0; i < 4; ++i)
#pragma unroll
            for (int reg = 0; reg < 4; ++reg) {
                red1[wr * 64 + i * 16 + q * 4 + reg] = mm1[i][reg];
                red2[wr * 64 + i * 16 + q * 4 + reg] = mm2[i][reg];
            }
    }
    __syncthreads();
    if (wc == 1 && c15 == 0) {
#pragma unroll
        for (int i = 0; i < 4; ++i)
#pragma unroll
            for (int reg = 0; reg < 4; ++reg) {
                int loc = wr * 64 + i * 16 + q * 4 + reg;
                ull m1 = mm1[i][reg];
                float m2 = mm2[i][reg];
                kmerge(m1, m2, red1[loc], red2[loc]);
                part1[(size_t)ct * BHW + row0 + loc] = m1;
                part2[(size_t)ct * BHW + row0 + loc] = m2;
            }
    }
}

// ---- fallback f32 main (validated R3) --------------------------------------
__global__ __launch_bounds__(NTH) void vq_main_f32(const float* __restrict__ z,
                                                   const float* __restrict__ emb,
                                                   const float* __restrict__ sume,
                                                   const float* __restrict__ t1g,
                                                   ull* __restrict__ part1,
                                                   float* __restrict__ part2) {
    __shared__ __align__(16) char smem[25344];
    float* zs = (float*)smem;
    float* es = zs + KT * ZSTR;
    ull* red1 = (ull*)smem;
    float* red2 = (float*)(smem + 16896);

    const int tid = threadIdx.x;
    const int rowtile = blockIdx.x & 255;
    const int split = blockIdx.x >> 8;
    const int row0 = rowtile * MT;
    const int b = row0 >> 10;
    const int hw0 = row0 & 1023;
    const int rg = tid & 15, cg = tid >> 4;
    const int sm = tid & 127, skh = tid >> 7;
    const int sn = tid >> 1, skq = tid & 1;

    const float* zstg = z + (size_t)b * BST + hw0 + sm;
    const int zi = (sm >> 3) * 10 + (sm & 7);
    const int ei = (sn >> 3) * 10 + (sn & 7);

    float t1v[RT];
#pragma unroll
    for (int i = 0; i < RT; ++i) t1v[i] = t1g[row0 + rg * RT + i];

    ull b1[RT];
    float b2[RT];
#pragma unroll
    for (int i = 0; i < RT; ++i) { b1[i] = ~0ull; b2[i] = 3.4e38f; }

    const int code0 = split * NT;
    float accf[RT][CTY];
#pragma unroll
    for (int i = 0; i < RT; ++i)
#pragma unroll
        for (int j = 0; j < CTY; ++j) accf[i][j] = 0.0f;

    float smv[CTY];
#pragma unroll
    for (int j = 0; j < CTY; ++j) smv[j] = sume[code0 + cg * CTY + j];

    const float* estg = emb + (size_t)(code0 + sn) * DIM + skq * 8;

    for (int kt = 0; kt < NKT; ++kt) {
        __syncthreads();
        {
            const float* zp = zstg + (size_t)(kt * KT + skh) * CST;
#pragma unroll
            for (int kk = 0; kk < 8; ++kk)
                zs[(kk * 2 + skh) * ZSTR + zi] = zp[(size_t)(kk * 2) * CST];
        }
        {
            const float4* ep = (const float4*)(estg + kt * KT);
            float4 e0 = ep[0], e1 = ep[1];
            float ev[8] = {e0.x, e0.y, e0.z, e0.w, e1.x, e1.y, e1.z, e1.w};
#pragma unroll
            for (int qq = 0; qq < 8; ++qq)
                es[(skq * 8 + qq) * ZSTR + ei] = ev[qq];
        }
        __syncthreads();

#pragma unroll 2
        for (int k = 0; k < KT; ++k) {
            const float* zf = &zs[k * ZSTR + rg * 10];
            const float* ef = &es[k * ZSTR + cg * 10];
            float zr[RT], er[CTY];
#pragma unroll
            for (int i = 0; i < RT; ++i) zr[i] = zf[i];
#pragma unroll
            for (int j = 0; j < CTY; ++j) er[j] = ef[j];
#pragma unroll
            for (int i = 0; i < RT; ++i)
#pragma unroll
                for (int j = 0; j < CTY; ++j)
                    accf[i][j] = fmaf(zr[i], er[j], accf[i][j]);
        }
    }

#pragma unroll
    for (int i = 0; i < RT; ++i)
#pragma unroll
        for (int j = 0; j < CTY; ++j) {
            float d = __fsub_rn(__fadd_rn(t1v[i], smv[j]),
                                __fmul_rn(2.0f, accf[i][j]));
            ull key = ((ull)__float_as_uint(d) << 32) |
                      (unsigned)(code0 + cg * CTY + j);
            kmerge(b1[i], b2[i], key, 3.4e38f);
        }

    __syncthreads();
#pragma unroll
    for (int i = 0; i < RT; ++i) {
        red1[cg * 132 + rg * RT + i] = b1[i];
        red2[cg * 132 + rg * RT + i] = b2[i];
    }
    __syncthreads();
    if (tid < MT) {
        ull m1 = red1[tid];
        float m2 = red2[tid];
#pragma unroll
        for (int c = 1; c < 16; ++c)
            kmerge(m1, m2, red1[c * 132 + tid], red2[c * 132 + tid]);
        part1[(size_t)split * BHW + row0 + tid] = m1;
        part2[(size_t)split * BHW + row0 + tid] = m2;
    }
}

// fallback t1 (reads global, validated R3)
__global__ __launch_bounds__(NTH) void vq_t1(const float* __restrict__ z,
                                             float* __restrict__ t1) {
    int n = blockIdx.x * NTH + threadIdx.x;
    int b = n >> 10, hw = n & 1023;
    const float* p = z + (size_t)b * BST + hw;
    float r[8], h[2];
#pragma unroll
    for (int half = 0; half < 2; ++half) {
        int c0 = half * 128;
#pragma unroll
        for (int k = 0; k < 8; ++k) {
            float v = p[(size_t)(c0 + k) * CST];
            r[k] = __fmul_rn(v, v);
        }
        for (int c = 8; c < 128; ++c) {
            float v = p[(size_t)(c0 + c) * CST];
            r[c & 7] = __fadd_rn(r[c & 7], __fmul_rn(v, v));
        }
        h[half] = __fadd_rn(
            __fadd_rn(__fadd_rn(r[0], r[1]), __fadd_rn(r[2], r[3])),
            __fadd_rn(__fadd_rn(r[4], r[5]), __fadd_rn(r[6], r[7])));
    }
    t1[n] = __fadd_rn(h[0], h[1]);
}

// ---- combine: final argmin, loss partial, flag narrow-gap rows -------------
__global__ __launch_bounds__(NTH) void vq_combine(const ull* __restrict__ part1,
                                                  const float* __restrict__ part2,
                                                  float* __restrict__ out,
                                                  float* __restrict__ bestd,
                                                  int* __restrict__ list,
                                                  int* __restrict__ cnt,
                                                  double* __restrict__ loss_acc,
                                                  float gapthr) {
    __shared__ double sdd[NTH];
    const int n = blockIdx.x * NTH + threadIdx.x;
    ull m1 = part1[n];
    float m2 = part2[n];
    for (int s = 1; s < 8; ++s)
        kmerge(m1, m2, part1[(size_t)s * BHW + n], part2[(size_t)s * BHW + n]);
    int j = (int)(m1 & 0xffffffffu);
    float d1 = keyhi(m1);
    out[n] = (float)j;
    bestd[n] = d1;
    float gap = __fsub_rn(m2, d1);
    if (!(gap >= gapthr)) {
        int p = atomicAdd(cnt, 1);
        list[p] = n;
    }
    sdd[threadIdx.x] = (double)d1;
    __syncthreads();
    for (int s = NTH / 2; s > 0; s >>= 1) {
        if (threadIdx.x < s) sdd[threadIdx.x] += sdd[threadIdx.x + s];
        __syncthreads();
    }
    if (threadIdx.x == 0) atomicAdd(loss_acc, sdd[0]);
}

// ---- batched exact f64 recheck (8 rows/block, coalesced embT) --------------
__global__ __launch_bounds__(NTH) void vq_recheck(const float* __restrict__ z,
                                                  const float* __restrict__ embT,
                                                  const float* __restrict__ sume,
                                                  const float* __restrict__ t1g,
                                                  const int* __restrict__ list,
                                                  const int* __restrict__ cnt,
                                                  float* __restrict__ out,
                                                  const float* __restrict__ bestd,
                                                  double* __restrict__ loss_acc) {
    __shared__ float zs[8][256];
    __shared__ ull sk[NTH];
    __shared__ int rows[8];
    const int t = threadIdx.x;
    int count = *cnt;
    if (count > BHW) count = BHW;

    for (int base = blockIdx.x * 8; base < count; base += 2048 * 8) {
        __syncthreads();
        if (t < 8) rows[t] = list[(base + t < count) ? base + t : count - 1];
        __syncthreads();
        {
            int r = t >> 5, ci = t & 31;
            int n = rows[r], bb = n >> 10, hw = n & 1023;
#pragma unroll
            for (int k = 0; k < 8; ++k) {
                int c = ci + k * 32;
                zs[r][c] = z[(size_t)bb * BST + (size_t)c * CST + hw];
            }
        }
        __syncthreads();

        double acc[8][4] = {};
        for (int c = 0; c < 256; ++c) {
            float e0 = embT[c * NE + t];
            float e1 = embT[c * NE + t + 256];
            float e2 = embT[c * NE + t + 512];
            float e3 = embT[c * NE + t + 768];
#pragma unroll
            for (int r = 0; r < 8; ++r) {
                double zv = (double)zs[r][c];
                acc[r][0] = fma(zv, (double)e0, acc[r][0]);
                acc[r][1] = fma(zv, (double)e1, acc[r][1]);
                acc[r][2] = fma(zv, (double)e2, acc[r][2]);
                acc[r][3] = fma(zv, (double)e3, acc[r][3]);
            }
        }
        for (int r = 0; r < 8; ++r) {
            int n = rows[r];
            float t1v = t1g[n];
            ull bk = ~0ull;
#pragma unroll
            for (int jj = 0; jj < 4; ++jj) {
                int j = t + jj * 256;
                float d = __fsub_rn(__fadd_rn(t1v, sume[j]),
                                    __fmul_rn(2.0f, (float)acc[r][jj]));
                ull key = ((ull)__float_as_uint(d) << 32) | (unsigned)j;
                if (key < bk) bk = key;
            }
            sk[t] = bk;
            __syncthreads();
            for (int s = NTH / 2; s > 0; s >>= 1) {
                if (t < s) { ull o = sk[t + s]; if (o < sk[t]) sk[t] = o; }
                __syncthreads();
            }
            if (t == 0 && base + r < count) {
                int j = (int)(sk[0] & 0xffffffffu);
                out[n] = (float)j;
                atomicAdd(loss_acc, (double)keyhi(sk[0]) - (double)bestd[n]);
            }
            __syncthreads();
        }
    }
}

__global__ void vq_final(const double* __restrict__ acc,
                         float* __restrict__ out) {
    double m = *acc / 8388608.0;
    float mf = (float)m;
    out[BHW] = __fadd_rn(mf, __fmul_rn(0.25f, mf));
}

extern "C" void kernel_launch(void* const* d_in, const int* in_sizes, int n_in,
                              void* d_out, int out_size, void* d_ws, size_t ws_size,
                              hipStream_t stream) {
    const float* z = (const float*)d_in[0];
    const float* emb = (const float*)d_in[1];
    float* out = (float*)d_out;

    char* ws = (char*)d_ws;
    float* sume = (float*)(ws + OFF_SUME);
    double* loss_acc = (double*)(ws + OFF_LOSS);
    int* cnt = (int*)(ws + OFF_CNT);
    float* t1 = (float*)(ws + OFF_T1);
    float* bestd = (float*)(ws + OFF_BESTD);
    int* list = (int*)(ws + OFF_LIST);
    float* embT = (float*)(ws + OFF_EMBT);
    ull* part1 = (ull*)(ws + OFF_PART1);
    float* part2 = (float*)(ws + OFF_PART2);
    unsigned short* Za = (unsigned short*)(ws + OFF_ZA);
    unsigned short* Eb = (unsigned short*)(ws + OFF_EB);

    const bool fast = ws_size >= WS_FAST_NEED;

    if (fast) {
        vq_prep<<<640, NTH, 0, stream>>>(emb, z, sume, embT, Eb, Za, t1,
                                         loss_acc, cnt, 1);
        vq_mfma<<<2048, NTH, 0, stream>>>(Za, Eb, sume, t1, part1, part2);
    } else {
        vq_prep<<<128, NTH, 0, stream>>>(emb, z, sume, embT, Eb, Za, t1,
                                         loss_acc, cnt, 0);
        vq_t1<<<BHW / NTH, NTH, 0, stream>>>(z, t1);
        vq_main_f32<<<2048, NTH, 0, stream>>>(z, emb, sume, t1, part1, part2);
    }
    vq_combine<<<BHW / NTH, NTH, 0, stream>>>(part1, part2, out, bestd, list, cnt,
                                              loss_acc, fast ? GAP_MFMA : GAP_F32);
    vq_recheck<<<2048, NTH, 0, stream>>>(z, embT, sume, t1, list, cnt, out, bestd,
                                         loss_acc);
    vq_final<<<1, 1, 0, stream>>>(loss_acc, out);
}

// Round 8
// 219.489 us; speedup vs baseline: 1.2880x; 1.2880x over previous
//
#include <hip/hip_runtime.h>

// VQ-VAE VectorQuantizer: z (32,256,32,32) f32, emb (1024,256) f32
// -> d_out: [32768 floats: argmin indices] + [1 float: loss]
//
// R8: recheck re-parallelized (R7 profile: recheck 107 us, only ~75 active
// blocks at 8 rows/block, latency-bound). Now 1 flagged row per block,
// thread t owns codes 4t..4t+3 via one coalesced float4 embT load per col.
// acc[4] f64 (8 VGPRs). ~600 active blocks.
// mfma/prep/combine unchanged from R7 (XCD map + 3-term split + swizzle).
// Numerics: d = fl(fl(t1+sume)-fl(2*dot)), numpy-pairwise sums, packed
// (f32bits<<32|j) first-occurrence argmin, exact-f64 recheck -- absmax 0
// validated R4-R7.

#define NE   1024
#define DIM  256
#define BHW  32768
#define CST  1024
#define BST  262144
#define NTH  256
#define MT   128
#define NT   128
#define KT   16
#define RT   8
#define CTY  8
#define ZSTR 160
#define NKT  (DIM / KT)
#define GAP_MFMA 1.5e-4f
#define GAP_F32  2.5e-4f

// workspace offsets (bytes)
#define OFF_SUME   0
#define OFF_LOSS   4096
#define OFF_CNT    4112
#define OFF_T1     8192
#define OFF_BESTD  139264
#define OFF_LIST   270336
#define OFF_EMBT   401408
#define OFF_PART1  1449984
#define OFF_PART2  3547136
#define OFF_ZA     5242880
#define OFF_EB     38797312
#define WS_FAST_NEED 40894464ull

typedef unsigned long long ull;
typedef __attribute__((ext_vector_type(8))) short bf16x8;
typedef __attribute__((ext_vector_type(4))) float f32x4;

__device__ __forceinline__ unsigned short bf16rne(float x) {
    unsigned u = __float_as_uint(x);
    return (unsigned short)((u + 0x7fffu + ((u >> 16) & 1u)) >> 16);
}

__device__ __forceinline__ void gll16(const void* g, void* l) {
    __builtin_amdgcn_global_load_lds(
        (const __attribute__((address_space(1))) unsigned int*)g,
        (__attribute__((address_space(3))) unsigned int*)l, 16, 0, 0);
}

__device__ __forceinline__ float keyhi(ull k) {
    return __uint_as_float((unsigned)(k >> 32));
}
__device__ __forceinline__ void kmerge(ull& m1, float& m2, ull x1, float x2) {
    if (x1 < m1) { m2 = fminf(x2, keyhi(m1)); m1 = x1; }
    else          m2 = fminf(m2, keyhi(x1));
}

__device__ __forceinline__ float np_pw128_sq_contig(const float* p) {
    float r[8];
#pragma unroll
    for (int k = 0; k < 8; ++k) r[k] = __fmul_rn(p[k], p[k]);
    for (int i = 8; i < 128; i += 8) {
#pragma unroll
        for (int k = 0; k < 8; ++k)
            r[k] = __fadd_rn(r[k], __fmul_rn(p[i + k], p[i + k]));
    }
    return __fadd_rn(__fadd_rn(__fadd_rn(r[0], r[1]), __fadd_rn(r[2], r[3])),
                     __fadd_rn(__fadd_rn(r[4], r[5]), __fadd_rn(r[6], r[7])));
}

// ---- merged prep: blocks 0..127 = e-side, 128.. = z-side -------------------
// Eb layout [kt 16][j 1024][pos 32]: kt<8 = b1(c=kt*32+pos), kt>=8 = b2.
// Za layout [kt 16][n 32768][32]:   kt<8 = a1,                kt>=8 = a2.
__global__ __launch_bounds__(NTH) void vq_prep(const float* __restrict__ emb,
                                               const float* __restrict__ z,
                                               float* __restrict__ sume,
                                               float* __restrict__ embT,
                                               unsigned short* __restrict__ Eb,
                                               unsigned short* __restrict__ Za,
                                               float* __restrict__ t1,
                                               double* __restrict__ loss_acc,
                                               int* __restrict__ cnt,
                                               int doEb) {
    __shared__ float zt[256 * 66];
    const int tid = threadIdx.x;

    if (blockIdx.x < 128) {
        // ---------------- e-side ----------------
        if (blockIdx.x == 0 && tid == 0) { *loss_acc = 0.0; *cnt = 0; }
        const int j0   = blockIdx.x * 8;
        const int jloc = tid >> 5;
        const int c0   = (tid & 31) * 8;
        const int j    = j0 + jloc;

        const float4* gp = (const float4*)(emb + (size_t)j * DIM + c0);
        float4 v0 = gp[0], v1 = gp[1];
        float v[8] = {v0.x, v0.y, v0.z, v0.w, v1.x, v1.y, v1.z, v1.w};

#pragma unroll
        for (int k = 0; k < 8; ++k) zt[jloc * 264 + c0 + k] = v[k];

        if (doEb) {
            bf16x8 p1, p2;
#pragma unroll
            for (int k = 0; k < 8; ++k) {
                unsigned short b1 = bf16rne(v[k]);
                float b1f = __uint_as_float((unsigned)b1 << 16);
                unsigned short b2 = bf16rne(__fsub_rn(v[k], b1f));
                p1[k] = (short)b1;
                p2[k] = (short)b2;
            }
            const int kta = c0 >> 5, pos = c0 & 31;
            *(bf16x8*)(Eb + (size_t)kta * 32768 + (size_t)j * 32 + pos)       = p1;
            *(bf16x8*)(Eb + (size_t)(kta + 8) * 32768 + (size_t)j * 32 + pos) = p2;
        }
        __syncthreads();
        {
            float col[8];
#pragma unroll
            for (int r = 0; r < 8; ++r) col[r] = zt[r * 264 + tid];
            float4 w0 = {col[0], col[1], col[2], col[3]};
            float4 w1 = {col[4], col[5], col[6], col[7]};
            *(float4*)(embT + (size_t)tid * NE + j0)     = w0;
            *(float4*)(embT + (size_t)tid * NE + j0 + 4) = w1;
        }
        if (tid < 8) {
            const float* p = &zt[tid * 264];
            sume[j0 + tid] = __fadd_rn(np_pw128_sq_contig(p),
                                       np_pw128_sq_contig(p + 128));
        }
        return;
    }

    // ---------------- z-side ----------------
    const int zb = blockIdx.x - 128;
    const int b = zb >> 4, hw0 = (zb & 15) * 64;
    const int idx = tid & 63, cq = tid >> 6;
    for (int c = cq * 64; c < cq * 64 + 64; ++c)
        zt[c * 66 + idx] = z[(size_t)b * BST + (size_t)c * CST + hw0 + idx];
    __syncthreads();
    if (tid < 64) {  // numpy-pairwise sum(z^2) per row, exact order
        float r[8], h[2];
#pragma unroll
        for (int half = 0; half < 2; ++half) {
            int c0 = half * 128;
#pragma unroll
            for (int k = 0; k < 8; ++k) {
                float v = zt[(c0 + k) * 66 + tid];
                r[k] = __fmul_rn(v, v);
            }
            for (int c = 8; c < 128; ++c) {
                float v = zt[(c0 + c) * 66 + tid];
                r[c & 7] = __fadd_rn(r[c & 7], __fmul_rn(v, v));
            }
            h[half] = __fadd_rn(
                __fadd_rn(__fadd_rn(r[0], r[1]), __fadd_rn(r[2], r[3])),
                __fadd_rn(__fadd_rn(r[4], r[5]), __fadd_rn(r[6], r[7])));
        }
        t1[b * 1024 + hw0 + tid] = __fadd_rn(h[0], h[1]);
    }
    const int l = tid & 63, seg = tid >> 6;
    const int rloc = seg * 16 + (l >> 2), piece = l & 3;
    const int n = b * 1024 + hw0 + rloc;
    for (int kt = 0; kt < 16; ++kt) {
        bf16x8 pack;
        int cbase = (kt & 7) * 32 + piece * 8;
#pragma unroll
        for (int jj = 0; jj < 8; ++jj) {
            float zf = zt[(cbase + jj) * 66 + rloc];
            unsigned short a1 = bf16rne(zf);
            unsigned short v = a1;
            if (kt >= 8) {
                float a1f = __uint_as_float((unsigned)a1 << 16);
                v = bf16rne(__fsub_rn(zf, a1f));
            }
            pack[jj] = (short)v;
        }
        *(bf16x8*)(Za + (size_t)kt * 1048576 + (size_t)n * 32 + piece * 8) = pack;
    }
}

// ---- MFMA distance GEMM: 128x128 tile, swizzled LDS, 3-term, XCD-mapped ----
__global__ __launch_bounds__(NTH) void vq_mfma(const unsigned short* __restrict__ Za,
                                               const unsigned short* __restrict__ Eb,
                                               const float* __restrict__ sume,
                                               const float* __restrict__ t1g,
                                               ull* __restrict__ part1,
                                               float* __restrict__ part2) {
    __shared__ __align__(16) unsigned short As[8192];  // lo|hi halves, swizzled
    __shared__ __align__(16) unsigned short Bs[8192];
    __shared__ ull   red1[128];
    __shared__ float red2[128];

    const int tid = threadIdx.x;
    const int w = tid >> 6, lane = tid & 63;
    const int wr = w & 1, wc = w >> 1;
    const int c15 = lane & 15, q = lane >> 4;
    // XCD-aware map: XCD = blk%8 (round-robin heuristic). 8 consecutive
    // blocks on one XCD = one rowtile x all 8 cts -> A-tile L2 reuse.
    const int blk = blockIdx.x;
    const int ct = (blk >> 3) & 7;
    const int rowtile = ((blk >> 6) << 3) | (blk & 7);
    const int row0 = rowtile * MT;

    const int perm = (lane >> 2) * 32 + (((lane & 3) ^ ((lane >> 3) & 3)) * 8);
    const int qs = (q ^ ((c15 >> 1) & 3)) * 8;

    f32x4 acc[4][4];
#pragma unroll
    for (int i = 0; i < 4; ++i)
#pragma unroll
        for (int jb = 0; jb < 4; ++jb) acc[i][jb] = (f32x4){0.f, 0.f, 0.f, 0.f};

    const int s0 = w * 2;
    for (int ktp = 0; ktp < 8; ++ktp) {
        __syncthreads();
        {
            const unsigned short* gAlo = Za + (size_t)ktp * 1048576 + (size_t)row0 * 32;
            const unsigned short* gAhi = gAlo + 8u * 1048576u;
            const unsigned short* gBlo = Eb + (size_t)ktp * 32768 + (size_t)ct * 4096;
            const unsigned short* gBhi = gBlo + 8u * 32768u;
#pragma unroll
            for (int ss = 0; ss < 2; ++ss) {
                const int s = s0 + ss;
                gll16(gAlo + s * 512 + perm, (void*)&As[s * 512]);
                gll16(gAhi + s * 512 + perm, (void*)&As[4096 + s * 512]);
                gll16(gBlo + s * 512 + perm, (void*)&Bs[s * 512]);
                gll16(gBhi + s * 512 + perm, (void*)&Bs[4096 + s * 512]);
            }
        }
        __syncthreads();

        bf16x8 bl[4], bh[4];
#pragma unroll
        for (int jb = 0; jb < 4; ++jb) {
            const int nn = (wc * 64 + jb * 16 + c15) * 32 + qs;
            bl[jb] = *(const bf16x8*)&Bs[nn];
            bh[jb] = *(const bf16x8*)&Bs[4096 + nn];
        }
#pragma unroll
        for (int i = 0; i < 4; ++i) {
            const int mm = (wr * 64 + i * 16 + c15) * 32 + qs;
            bf16x8 al = *(const bf16x8*)&As[mm];
            bf16x8 ah = *(const bf16x8*)&As[4096 + mm];
#pragma unroll
            for (int jb = 0; jb < 4; ++jb) {
                acc[i][jb] = __builtin_amdgcn_mfma_f32_16x16x32_bf16(
                    al, bl[jb], acc[i][jb], 0, 0, 0);
                acc[i][jb] = __builtin_amdgcn_mfma_f32_16x16x32_bf16(
                    al, bh[jb], acc[i][jb], 0, 0, 0);
                acc[i][jb] = __builtin_amdgcn_mfma_f32_16x16x32_bf16(
                    ah, bl[jb], acc[i][jb], 0, 0, 0);
            }
        }
    }

    // epilogue: d = fl(fl(t1+sume) - fl(2*dot)); per-row best/2nd over 128 codes
    float sme[4];
#pragma unroll
    for (int jb = 0; jb < 4; ++jb)
        sme[jb] = sume[ct * 128 + wc * 64 + jb * 16 + c15];

    ull   mm1[4][4];
    float mm2[4][4];
#pragma unroll
    for (int i = 0; i < 4; ++i) {
#pragma unroll
        for (int reg = 0; reg < 4; ++reg) {
            int row = row0 + wr * 64 + i * 16 + q * 4 + reg;
            float t1v = t1g[row];
            ull m1 = ~0ull;
            float m2 = 3.4e38f;
#pragma unroll
            for (int jb = 0; jb < 4; ++jb) {
                float d = __fsub_rn(__fadd_rn(t1v, sme[jb]),
                                    __fmul_rn(2.0f, acc[i][jb][reg]));
                ull key = ((ull)__float_as_uint(d) << 32) |
                          (unsigned)(ct * 128 + wc * 64 + jb * 16 + c15);
                kmerge(m1, m2, key, 3.4e38f);
            }
#pragma unroll
            for (int m = 1; m < 16; m <<= 1) {
                ull x1 = __shfl_xor(m1, m);
                float x2 = __shfl_xor(m2, m);
                kmerge(m1, m2, x1, x2);
            }
            mm1[i][reg] = m1;
            mm2[i][reg] = m2;
        }
    }
    if (wc == 0 && c15 == 0) {
#pragma unroll
        for (int i = 0; i < 4; ++i)
#pragma unroll
            for (int reg = 0; reg < 4; ++reg) {
                red1[wr * 64 + i * 16 + q * 4 + reg] = mm1[i][reg];
                red2[wr * 64 + i * 16 + q * 4 + reg] = mm2[i][reg];
            }
    }
    __syncthreads();
    if (wc == 1 && c15 == 0) {
#pragma unroll
        for (int i = 0; i < 4; ++i)
#pragma unroll
            for (int reg = 0; reg < 4; ++reg) {
                int loc = wr * 64 + i * 16 + q * 4 + reg;
                ull m1 = mm1[i][reg];
                float m2 = mm2[i][reg];
                kmerge(m1, m2, red1[loc], red2[loc]);
                part1[(size_t)ct * BHW + row0 + loc] = m1;
                part2[(size_t)ct * BHW + row0 + loc] = m2;
            }
    }
}

// ---- fallback f32 main (validated R3) --------------------------------------
__global__ __launch_bounds__(NTH) void vq_main_f32(const float* __restrict__ z,
                                                   const float* __restrict__ emb,
                                                   const float* __restrict__ sume,
                                                   const float* __restrict__ t1g,
                                                   ull* __restrict__ part1,
                                                   float* __restrict__ part2) {
    __shared__ __align__(16) char smem[25344];
    float* zs = (float*)smem;
    float* es = zs + KT * ZSTR;
    ull* red1 = (ull*)smem;
    float* red2 = (float*)(smem + 16896);

    const int tid = threadIdx.x;
    const int rowtile = blockIdx.x & 255;
    const int split = blockIdx.x >> 8;
    const int row0 = rowtile * MT;
    const int b = row0 >> 10;
    const int hw0 = row0 & 1023;
    const int rg = tid & 15, cg = tid >> 4;
    const int sm = tid & 127, skh = tid >> 7;
    const int sn = tid >> 1, skq = tid & 1;

    const float* zstg = z + (size_t)b * BST + hw0 + sm;
    const int zi = (sm >> 3) * 10 + (sm & 7);
    const int ei = (sn >> 3) * 10 + (sn & 7);

    float t1v[RT];
#pragma unroll
    for (int i = 0; i < RT; ++i) t1v[i] = t1g[row0 + rg * RT + i];

    ull b1[RT];
    float b2[RT];
#pragma unroll
    for (int i = 0; i < RT; ++i) { b1[i] = ~0ull; b2[i] = 3.4e38f; }

    const int code0 = split * NT;
    float accf[RT][CTY];
#pragma unroll
    for (int i = 0; i < RT; ++i)
#pragma unroll
        for (int j = 0; j < CTY; ++j) accf[i][j] = 0.0f;

    float smv[CTY];
#pragma unroll
    for (int j = 0; j < CTY; ++j) smv[j] = sume[code0 + cg * CTY + j];

    const float* estg = emb + (size_t)(code0 + sn) * DIM + skq * 8;

    for (int kt = 0; kt < NKT; ++kt) {
        __syncthreads();
        {
            const float* zp = zstg + (size_t)(kt * KT + skh) * CST;
#pragma unroll
            for (int kk = 0; kk < 8; ++kk)
                zs[(kk * 2 + skh) * ZSTR + zi] = zp[(size_t)(kk * 2) * CST];
        }
        {
            const float4* ep = (const float4*)(estg + kt * KT);
            float4 e0 = ep[0], e1 = ep[1];
            float ev[8] = {e0.x, e0.y, e0.z, e0.w, e1.x, e1.y, e1.z, e1.w};
#pragma unroll
            for (int qq = 0; qq < 8; ++qq)
                es[(skq * 8 + qq) * ZSTR + ei] = ev[qq];
        }
        __syncthreads();

#pragma unroll 2
        for (int k = 0; k < KT; ++k) {
            const float* zf = &zs[k * ZSTR + rg * 10];
            const float* ef = &es[k * ZSTR + cg * 10];
            float zr[RT], er[CTY];
#pragma unroll
            for (int i = 0; i < RT; ++i) zr[i] = zf[i];
#pragma unroll
            for (int j = 0; j < CTY; ++j) er[j] = ef[j];
#pragma unroll
            for (int i = 0; i < RT; ++i)
#pragma unroll
                for (int j = 0; j < CTY; ++j)
                    accf[i][j] = fmaf(zr[i], er[j], accf[i][j]);
        }
    }

#pragma unroll
    for (int i = 0; i < RT; ++i)
#pragma unroll
        for (int j = 0; j < CTY; ++j) {
            float d = __fsub_rn(__fadd_rn(t1v[i], smv[j]),
                                __fmul_rn(2.0f, accf[i][j]));
            ull key = ((ull)__float_as_uint(d) << 32) |
                      (unsigned)(code0 + cg * CTY + j);
            kmerge(b1[i], b2[i], key, 3.4e38f);
        }

    __syncthreads();
#pragma unroll
    for (int i = 0; i < RT; ++i) {
        red1[cg * 132 + rg * RT + i] = b1[i];
        red2[cg * 132 + rg * RT + i] = b2[i];
    }
    __syncthreads();
    if (tid < MT) {
        ull m1 = red1[tid];
        float m2 = red2[tid];
#pragma unroll
        for (int c = 1; c < 16; ++c)
            kmerge(m1, m2, red1[c * 132 + tid], red2[c * 132 + tid]);
        part1[(size_t)split * BHW + row0 + tid] = m1;
        part2[(size_t)split * BHW + row0 + tid] = m2;
    }
}

// fallback t1 (reads global, validated R3)
__global__ __launch_bounds__(NTH) void vq_t1(const float* __restrict__ z,
                                             float* __restrict__ t1) {
    int n = blockIdx.x * NTH + threadIdx.x;
    int b = n >> 10, hw = n & 1023;
    const float* p = z + (size_t)b * BST + hw;
    float r[8], h[2];
#pragma unroll
    for (int half = 0; half < 2; ++half) {
        int c0 = half * 128;
#pragma unroll
        for (int k = 0; k < 8; ++k) {
            float v = p[(size_t)(c0 + k) * CST];
            r[k] = __fmul_rn(v, v);
        }
        for (int c = 8; c < 128; ++c) {
            float v = p[(size_t)(c0 + c) * CST];
            r[c & 7] = __fadd_rn(r[c & 7], __fmul_rn(v, v));
        }
        h[half] = __fadd_rn(
            __fadd_rn(__fadd_rn(r[0], r[1]), __fadd_rn(r[2], r[3])),
            __fadd_rn(__fadd_rn(r[4], r[5]), __fadd_rn(r[6], r[7])));
    }
    t1[n] = __fadd_rn(h[0], h[1]);
}

// ---- combine: final argmin, loss partial, flag narrow-gap rows -------------
__global__ __launch_bounds__(NTH) void vq_combine(const ull* __restrict__ part1,
                                                  const float* __restrict__ part2,
                                                  float* __restrict__ out,
                                                  float* __restrict__ bestd,
                                                  int* __restrict__ list,
                                                  int* __restrict__ cnt,
                                                  double* __restrict__ loss_acc,
                                                  float gapthr) {
    __shared__ double sdd[NTH];
    const int n = blockIdx.x * NTH + threadIdx.x;
    ull m1 = part1[n];
    float m2 = part2[n];
    for (int s = 1; s < 8; ++s)
        kmerge(m1, m2, part1[(size_t)s * BHW + n], part2[(size_t)s * BHW + n]);
    int j = (int)(m1 & 0xffffffffu);
    float d1 = keyhi(m1);
    out[n] = (float)j;
    bestd[n] = d1;
    float gap = __fsub_rn(m2, d1);
    if (!(gap >= gapthr)) {
        int p = atomicAdd(cnt, 1);
        list[p] = n;
    }
    sdd[threadIdx.x] = (double)d1;
    __syncthreads();
    for (int s = NTH / 2; s > 0; s >>= 1) {
        if (threadIdx.x < s) sdd[threadIdx.x] += sdd[threadIdx.x + s];
        __syncthreads();
    }
    if (threadIdx.x == 0) atomicAdd(loss_acc, sdd[0]);
}

// ---- exact f64 recheck: 1 flagged row per block, float4 embT codes ---------
// thread t owns codes 4t..4t+3; embT col read = one coalesced float4/thread.
__global__ __launch_bounds__(NTH) void vq_recheck(const float* __restrict__ z,
                                                  const float* __restrict__ embT,
                                                  const float* __restrict__ sume,
                                                  const float* __restrict__ t1g,
                                                  const int* __restrict__ list,
                                                  const int* __restrict__ cnt,
                                                  float* __restrict__ out,
                                                  const float* __restrict__ bestd,
                                                  double* __restrict__ loss_acc) {
    __shared__ float zs[DIM];
    __shared__ ull sk[NTH];
    const int t = threadIdx.x;
    int count = *cnt;
    if (count > BHW) count = BHW;
    const float4* ev = (const float4*)embT;   // [c][j/4]

    for (int li = blockIdx.x; li < count; li += gridDim.x) {
        const int n = list[li];
        const int bb = n >> 10, hw = n & 1023;
        __syncthreads();   // previous iteration's zs readers done
        zs[t] = z[(size_t)bb * BST + (size_t)t * CST + hw];
        __syncthreads();

        double acc[4] = {0.0, 0.0, 0.0, 0.0};
#pragma unroll 4
        for (int c = 0; c < DIM; ++c) {
            float4 e = ev[c * 256 + t];
            double zv = (double)zs[c];
            acc[0] = fma(zv, (double)e.x, acc[0]);
            acc[1] = fma(zv, (double)e.y, acc[1]);
            acc[2] = fma(zv, (double)e.z, acc[2]);
            acc[3] = fma(zv, (double)e.w, acc[3]);
        }
        const float t1v = t1g[n];
        const float4 sm = ((const float4*)sume)[t];
        const float smv[4] = {sm.x, sm.y, sm.z, sm.w};
        ull bk = ~0ull;
#pragma unroll
        for (int jj = 0; jj < 4; ++jj) {
            int j = t * 4 + jj;
            float d = __fsub_rn(__fadd_rn(t1v, smv[jj]),
                                __fmul_rn(2.0f, (float)acc[jj]));
            ull key = ((ull)__float_as_uint(d) << 32) | (unsigned)j;
            if (key < bk) bk = key;
        }
        sk[t] = bk;
        __syncthreads();
        for (int s = NTH / 2; s > 0; s >>= 1) {
            if (t < s) { ull o = sk[t + s]; if (o < sk[t]) sk[t] = o; }
            __syncthreads();
        }
        if (t == 0) {
            int j = (int)(sk[0] & 0xffffffffu);
            out[n] = (float)j;
            atomicAdd(loss_acc, (double)keyhi(sk[0]) - (double)bestd[n]);
        }
    }
}

__global__ void vq_final(const double* __restrict__ acc,
                         float* __restrict__ out) {
    double m = *acc / 8388608.0;
    float mf = (float)m;
    out[BHW] = __fadd_rn(mf, __fmul_rn(0.25f, mf));
}

extern "C" void kernel_launch(void* const* d_in, const int* in_sizes, int n_in,
                              void* d_out, int out_size, void* d_ws, size_t ws_size,
                              hipStream_t stream) {
    const float* z = (const float*)d_in[0];
    const float* emb = (const float*)d_in[1];
    float* out = (float*)d_out;

    char* ws = (char*)d_ws;
    float* sume = (float*)(ws + OFF_SUME);
    double* loss_acc = (double*)(ws + OFF_LOSS);
    int* cnt = (int*)(ws + OFF_CNT);
    float* t1 = (float*)(ws + OFF_T1);
    float* bestd = (float*)(ws + OFF_BESTD);
    int* list = (int*)(ws + OFF_LIST);
    float* embT = (float*)(ws + OFF_EMBT);
    ull* part1 = (ull*)(ws + OFF_PART1);
    float* part2 = (float*)(ws + OFF_PART2);
    unsigned short* Za = (unsigned short*)(ws + OFF_ZA);
    unsigned short* Eb = (unsigned short*)(ws + OFF_EB);

    const bool fast = ws_size >= WS_FAST_NEED;

    if (fast) {
        vq_prep<<<640, NTH, 0, stream>>>(emb, z, sume, embT, Eb, Za, t1,
                                         loss_acc, cnt, 1);
        vq_mfma<<<2048, NTH, 0, stream>>>(Za, Eb, sume, t1, part1, part2);
    } else {
        vq_prep<<<128, NTH, 0, stream>>>(emb, z, sume, embT, Eb, Za, t1,
                                         loss_acc, cnt, 0);
        vq_t1<<<BHW / NTH, NTH, 0, stream>>>(z, t1);
        vq_main_f32<<<2048, NTH, 0, stream>>>(z, emb, sume, t1, part1, part2);
    }
    vq_combine<<<BHW / NTH, NTH, 0, stream>>>(part1, part2, out, bestd, list, cnt,
                                              loss_acc, fast ? GAP_MFMA : GAP_F32);
    vq_recheck<<<2048, NTH, 0, stream>>>(z, embT, sume, t1, list, cnt, out, bestd,
                                         loss_acc);
    vq_final<<<1, 1, 0, stream>>>(loss_acc, out);
}